// Round 1
// baseline (740.634 us; speedup 1.0000x reference)
//
#include <hip/hip_runtime.h>

// AblationDecoder: B=8, N=50000, DIM=3, C_DIM=64, TASK_DIM=512, H=64, NB=5, OUT=12
// R5: weights in LDS. The R4 kernel was latency-bound (MfmaUtil 20%, VALU 29%,
// HBM 9%, ~2 waves/SIMD because net4 AGPRs + 124 VGPRs ~ 190 unified regs):
// each 1-wave block re-read the full 123KB weight set from L2 every 64 points,
// and with no co-resident waves to hide ~200-400cy L2 latency, ~2/3 of wave
// time was vmcnt stall. R5 uses 256 persistent blocks x 512 threads (8 waves,
// 1 block/CU), stages the whole weight set (124,928B) into LDS once via
// global_load_lds, then each wave loops over 4-tile tasks reading fragments
// with ds_read_b128 (~120cy, covered by the existing stage-ahead prefetch).
// Biases/tp/fc_p_W stay global (tiny, L1-hot) to keep the LDS pipe for weights.
#define B_    8
#define N_    50000
#define NB_   5
#define OUT_  12
#define TILES_ 4
#define TILES_PER_BATCH 3125              // 50000/16
#define BLOCKS_PER_BATCH 782              // ceil(3125/4)
#define NTASKS (B_ * BLOCKS_PER_BATCH)    // 6256
#define GRID_  256
#define NWAVES_TOTAL (GRID_ * 8)          // 2048

typedef _Float16 half8 __attribute__((ext_vector_type(8)));
typedef float   floatx4 __attribute__((ext_vector_type(4)));

// async 16B global->LDS (dest = wave-uniform base + lane*16)
__device__ __forceinline__ void cp16_async(const void* g, void* l) {
    __builtin_amdgcn_global_load_lds(
        (const __attribute__((address_space(1))) unsigned int*)g,
        (__attribute__((address_space(3))) unsigned int*)l,
        16, 0, 0);
}

// B fragment from two D-layout accumulators: f32->f16 (RTN), then packed relu.
// relu-after-cvt == cvt-after-relu (cvt monotone, cvt(0)=0) but emits
// v_pk_max_f16 (4 ops) instead of 8 scalar f32 max.
__device__ __forceinline__ half8 packB(floatx4 a, floatx4 b) {
    half8 r;
    r[0] = (_Float16)a[0]; r[1] = (_Float16)a[1];
    r[2] = (_Float16)a[2]; r[3] = (_Float16)a[3];
    r[4] = (_Float16)b[0]; r[5] = (_Float16)b[1];
    r[6] = (_Float16)b[2]; r[7] = (_Float16)b[3];
    half8 z = {(_Float16)0, (_Float16)0, (_Float16)0, (_Float16)0,
               (_Float16)0, (_Float16)0, (_Float16)0, (_Float16)0};
    return __builtin_elementwise_max(r, z);
}

// load one stage's 8 A-fragments from LDS (frag j = A[T*2+h]) -> ds_read_b128 x8
__device__ __forceinline__ void lds8(half8 (&A)[8], const _Float16* base, int lane) {
    #pragma unroll
    for (int T = 0; T < 4; ++T)
        #pragma unroll
        for (int h = 0; h < 2; ++h)
            A[T * 2 + h] = *(const half8*)(base + (size_t)(T * 128 + h * 64 + lane) * 8);
}

// ---------------------------------------------------------------------------
// Pre-kernel A (fused): blocks 0..31 build f16 A-fragment weights (R replicas);
// blocks 32..111 compute task-feature partial projections (8 chunks per (b,i)).
// ws_w layout per replica: chunk ((mat*5+i)*4+T)*128 + h*64 + q*16 + m15, 8 halves.
// ws_fco per replica: 512 chunks, chunks 0..127 = fc_out, rest zero.
// (unchanged from R4)
// ---------------------------------------------------------------------------
__global__ void prep_kernel(const float* __restrict__ fc_c_W,
                            const float* __restrict__ blk0_W,
                            const float* __restrict__ blk1_W,
                            const float* __restrict__ fc_out_W,
                            const float* __restrict__ tf,
                            _Float16* __restrict__ ws_w,
                            _Float16* __restrict__ ws_fco,
                            float* __restrict__ partials, int R) {
    int bid = blockIdx.x, tid = threadIdx.x;
    if (bid < 32) {
        int u = bid * 256 + tid;          // 0..8191
        if (u < 7680) {
            int m15 = u & 15, q = (u >> 4) & 3, h = (u >> 6) & 1, T = (u >> 7) & 3;
            int mi = u >> 9;              // 0..14
            int mat = mi / 5, i = mi % 5;
            int n = T * 16 + m15;
            _Float16 out[8];
            #pragma unroll
            for (int j = 0; j < 8; ++j) {
                float v;
                if (mat == 0) {
                    int k = 32 * h + 8 * q + j;
                    v = fc_c_W[((size_t)i * 576 + k) * 64 + n];
                } else {
                    int f = 32 * h + 16 * (j >> 2) + 4 * q + (j & 3);
                    const float* W = (mat == 1) ? blk0_W : blk1_W;
                    v = W[((size_t)i * 64 + f) * 64 + n];
                }
                out[j] = (_Float16)v;
            }
            uint4 val = *(uint4*)out;
            for (int r = 0; r < R; ++r)
                *(uint4*)(ws_w + (size_t)r * 61440 + (size_t)u * 8) = val;
        } else {
            int e = u - 7680;             // 0..511
            _Float16 out[8] = {};
            if (e < 128) {
                int m15 = e & 15, q = (e >> 4) & 3, h = (e >> 6) & 1;
                #pragma unroll
                for (int j = 0; j < 8; ++j) {
                    int f = 32 * h + 16 * (j >> 2) + 4 * q + (j & 3);
                    out[j] = (m15 < OUT_) ? (_Float16)fc_out_W[f * OUT_ + m15] : (_Float16)0.f;
                }
            }
            uint4 val = *(uint4*)out;
            for (int r = 0; r < R; ++r)
                *(uint4*)(ws_fco + (size_t)r * 4096 + (size_t)e * 8) = val;
        }
    } else {
        // task partials: idx2 -> (b, i, half); 4 groups of 64 t's each
        int idx2 = bid - 32;              // 0..79
        int b = idx2 / 10, rem = idx2 % 10, i = rem >> 1, hf = rem & 1;
        int g = tid >> 6, j = tid & 63;
        const float* W  = fc_c_W + ((size_t)i * 576 + 64) * 64;
        const float* tb = tf + b * 512;
        int t0 = hf * 256 + g * 64;
        float acc = 0.f;
        #pragma unroll 8
        for (int t = 0; t < 64; ++t)
            acc += tb[t0 + t] * W[(size_t)(t0 + t) * 64 + j];
        partials[(((b * 5 + i) << 3) + (hf * 4 + g)) * 64 + j] = acc;
    }
}

// Pre-kernel B: tp[b][i][j] = sum_8 partials + fc_c_b + (i==0 ? fc_p_b : 0)
__global__ void finalize_tp(const float* __restrict__ partials,
                            const float* __restrict__ fc_c_b,
                            const float* __restrict__ fc_p_b,
                            float* __restrict__ tp) {
    int u = blockIdx.x * 256 + threadIdx.x;
    if (u >= 2560) return;
    int b = u / 320, rem = u % 320, i = rem >> 6, j = rem & 63;
    float s = fc_c_b[i * 64 + j] + ((i == 0) ? fc_p_b[j] : 0.f);
    #pragma unroll
    for (int k = 0; k < 8; ++k)
        s += partials[(((b * 5 + i) << 3) + k) * 64 + j];
    tp[u] = s;
}

// ---------------------------------------------------------------------------
// One resblock: cond (Ac) -> [prefetch blk1 into Ac from LDS] -> blk0 (Ab) +
// blk1 (Ac) fused per tile -> [prefetch next cond into Ab] -> [prefetch next
// blk0 into Ac]. Caller alternates (X,Y)/(Y,X). On the last call only the two
// live fc_out fragments are loaded.
// ---------------------------------------------------------------------------
__device__ __forceinline__ void resblock(
    half8 (&Ac)[8], half8 (&Ab)[8],
    floatx4 (&net4)[TILES_][4], const half8 (&cB)[TILES_][2],
    int tc, int i, int q, int lane,
    const float* __restrict__ tp_b, const float* __restrict__ b0g,
    const float* __restrict__ b1g, const _Float16* wlds,
    const _Float16* next_base, bool last)
{
    floatx4 tpv[4], bb0[4], bb1[4];
    #pragma unroll
    for (int T = 0; T < 4; ++T) {
        int off = i * 64 + 16 * T + 4 * q;
        tpv[T] = *(const floatx4*)(tp_b + off);
        bb0[T] = *(const floatx4*)(b0g + off);
        bb1[T] = *(const floatx4*)(b1g + off);
    }
    // ---- conditioning: net += c @ Wc + tp ----
    #pragma unroll
    for (int t = 0; t < TILES_; ++t) {
        if (t >= tc) break;
        #pragma unroll
        for (int T = 0; T < 4; ++T) {
            floatx4 a = net4[t][T];
            a = __builtin_amdgcn_mfma_f32_16x16x32_f16(Ac[2 * T], cB[t][0], a, 0, 0, 0);
            a = __builtin_amdgcn_mfma_f32_16x16x32_f16(Ac[2 * T + 1], cB[t][1], a, 0, 0, 0);
            net4[t][T] = a + tpv[T];
        }
    }
    lds8(Ac, wlds + (size_t)(10 + i) * 4096, lane);      // prefetch blk1_i
    // ---- blk0+blk1 fused per tile ----
    #pragma unroll
    for (int t = 0; t < TILES_; ++t) {
        if (t >= tc) break;
        half8 Bn0 = packB(net4[t][0], net4[t][1]);
        half8 Bn1 = packB(net4[t][2], net4[t][3]);
        floatx4 hh[4];
        #pragma unroll
        for (int T = 0; T < 4; ++T) {
            floatx4 a = bb0[T];
            a = __builtin_amdgcn_mfma_f32_16x16x32_f16(Ab[2 * T], Bn0, a, 0, 0, 0);
            a = __builtin_amdgcn_mfma_f32_16x16x32_f16(Ab[2 * T + 1], Bn1, a, 0, 0, 0);
            hh[T] = a;
        }
        half8 Bh0 = packB(hh[0], hh[1]);
        half8 Bh1 = packB(hh[2], hh[3]);
        #pragma unroll
        for (int T = 0; T < 4; ++T) {
            floatx4 a = bb1[T];
            a = __builtin_amdgcn_mfma_f32_16x16x32_f16(Ac[2 * T], Bh0, a, 0, 0, 0);
            a = __builtin_amdgcn_mfma_f32_16x16x32_f16(Ac[2 * T + 1], Bh1, a, 0, 0, 0);
            net4[t][T] += a;
        }
    }
    if (!last) {
        lds8(Ab, next_base, lane);                           // prefetch cond_{i+1}
        lds8(Ac, wlds + (size_t)(5 + i + 1) * 4096, lane);   // prefetch blk0_{i+1}
    } else {
        // fc_out: only frags 0,1 are ever used
        Ab[0] = *(const half8*)(next_base + (size_t)lane * 8);
        Ab[1] = *(const half8*)(next_base + (size_t)(64 + lane) * 8);
    }
}

// ---------------------------------------------------------------------------
// Main decoder: 256 persistent blocks x 512 threads (8 waves, 1 block/CU via
// 124,928B LDS). Weights staged to LDS once; each wave loops over 4-tile tasks.
// Replica = blockIdx & rmask == XCD id -> per-XCD L2-local staging.
// ---------------------------------------------------------------------------
__global__ __launch_bounds__(512, 2) void decoder_kernel(
    const float* __restrict__ p_g, const float* __restrict__ c_g,
    const float* __restrict__ blk0_b, const float* __restrict__ blk1_b,
    const float* __restrict__ fc_p_W, const float* __restrict__ fc_out_b,
    const _Float16* __restrict__ ws_w, const _Float16* __restrict__ ws_fco,
    const float* __restrict__ tp_g, float* __restrict__ out_g, int rmask)
{
    // 15 stages * 4096 halves + 1024 halves fc_out = 62464 halves = 124,928 B
    __shared__ __align__(16) _Float16 wlds[62464];

    const int tid  = threadIdx.x;
    const int wave = tid >> 6;
    const int lane = tid & 63;
    const int q = lane >> 4, m15 = lane & 15;
    const _Float16* wsr = ws_w  + (size_t)(blockIdx.x & rmask) * 61440;
    const _Float16* fcr = ws_fco + (size_t)(blockIdx.x & rmask) * 4096;

    // ---- stage all weights into LDS: 7680 weight chunks + 128 fc_out chunks ----
    #pragma unroll
    for (int k = 0; k < 16; ++k) {
        int cb = k * 512 + wave * 64;               // wave-uniform chunk base
        if (cb < 7808) {
            const _Float16* src = (cb < 7680) ? (wsr + (size_t)cb * 8)
                                              : (fcr + (size_t)(cb - 7680) * 8);
            cp16_async(src + (size_t)lane * 8, (char*)&wlds[0] + (size_t)cb * 16);
        }
    }
    __syncthreads();   // drains vmcnt(0): staging complete; LDS read-only after

    // ---- per-wave task loop ----
    for (int task = blockIdx.x * 8 + wave; task < NTASKS; task += NWAVES_TOTAL) {
        const int batch = task / BLOCKS_PER_BATCH;
        const int blk   = task % BLOCKS_PER_BATCH;
        const int tile0 = blk * TILES_;
        const int tc    = min(TILES_, TILES_PER_BATCH - tile0);
        const long gbase = (long)batch * N_ + (long)tile0 * 16;
        const float* tp_b = tp_g + batch * (NB_ * 64);

        // ---- c -> B-operand registers (global; issue first, longest latency) ----
        half8 cB[TILES_][2];
        #pragma unroll
        for (int t = 0; t < TILES_; ++t) {
            if (t >= tc) break;
            const float* cr = c_g + (size_t)(gbase + t * 16 + m15) * 64;
            #pragma unroll
            for (int h = 0; h < 2; ++h) {
                float4 v0 = *(const float4*)(cr + 32 * h + 8 * q);
                float4 v1 = *(const float4*)(cr + 32 * h + 8 * q + 4);
                half8 r;
                r[0] = (_Float16)v0.x; r[1] = (_Float16)v0.y;
                r[2] = (_Float16)v0.z; r[3] = (_Float16)v0.w;
                r[4] = (_Float16)v1.x; r[5] = (_Float16)v1.y;
                r[6] = (_Float16)v1.z; r[7] = (_Float16)v1.w;
                cB[t][h] = r;
            }
        }

        // ---- initial fragment prefetch from LDS ----
        half8 X[8], Y[8];
        lds8(X, &wlds[0], lane);                          // cond_0
        lds8(Y, &wlds[0] + (size_t)5 * 4096, lane);       // blk0_0

        // ---- net init: p @ fc_p_W (biases folded into tp[0]) ----
        floatx4 fw[3][4];
        #pragma unroll
        for (int d = 0; d < 3; ++d)
            #pragma unroll
            for (int T = 0; T < 4; ++T)
                fw[d][T] = *(const floatx4*)(fc_p_W + d * 64 + 16 * T + 4 * q);
        floatx4 net4[TILES_][4];
        #pragma unroll
        for (int t = 0; t < TILES_; ++t) {
            if (t >= tc) break;
            long g = gbase + t * 16 + m15;
            float pp0 = p_g[g * 3 + 0], pp1 = p_g[g * 3 + 1], pp2 = p_g[g * 3 + 2];
            #pragma unroll
            for (int T = 0; T < 4; ++T)
                net4[t][T] = fw[0][T] * pp0 + fw[1][T] * pp1 + fw[2][T] * pp2;
        }

        // ---- 5 resblocks, alternating prefetch buffers (all weights from LDS) ----
        resblock(X, Y, net4, cB, tc, 0, q, lane, tp_b, blk0_b, blk1_b, &wlds[0], &wlds[0] + (size_t)1 * 4096, false);
        resblock(Y, X, net4, cB, tc, 1, q, lane, tp_b, blk0_b, blk1_b, &wlds[0], &wlds[0] + (size_t)2 * 4096, false);
        resblock(X, Y, net4, cB, tc, 2, q, lane, tp_b, blk0_b, blk1_b, &wlds[0], &wlds[0] + (size_t)3 * 4096, false);
        resblock(Y, X, net4, cB, tc, 3, q, lane, tp_b, blk0_b, blk1_b, &wlds[0], &wlds[0] + (size_t)4 * 4096, false);
        resblock(X, Y, net4, cB, tc, 4, q, lane, tp_b, blk0_b, blk1_b, &wlds[0], &wlds[0] + (size_t)61440, true);

        // ---- output: out = relu(net) @ fc_out + b  (fco frags in Y[0],Y[1]) ----
        floatx4 ob = {0.f, 0.f, 0.f, 0.f};
        if (q < 3) ob = *(const floatx4*)(fc_out_b + 4 * q);
        #pragma unroll
        for (int t = 0; t < TILES_; ++t) {
            if (t >= tc) break;
            half8 Bn0 = packB(net4[t][0], net4[t][1]);
            half8 Bn1 = packB(net4[t][2], net4[t][3]);
            floatx4 a = ob;
            a = __builtin_amdgcn_mfma_f32_16x16x32_f16(Y[0], Bn0, a, 0, 0, 0);
            a = __builtin_amdgcn_mfma_f32_16x16x32_f16(Y[1], Bn1, a, 0, 0, 0);
            if (q < 3) {
                long g = gbase + t * 16 + m15;
                *(float4*)(out_g + g * OUT_ + 4 * q) = make_float4(a[0], a[1], a[2], a[3]);
            }
        }
    }
}

// ---------------------------------------------------------------------------
extern "C" void kernel_launch(void* const* d_in, const int* in_sizes, int n_in,
                              void* d_out, int out_size, void* d_ws, size_t ws_size,
                              hipStream_t stream) {
    const float* p        = (const float*)d_in[0];
    const float* c        = (const float*)d_in[1];
    const float* tf       = (const float*)d_in[2];
    const float* fc_p_W   = (const float*)d_in[3];
    const float* fc_p_b   = (const float*)d_in[4];
    const float* fc_c_W   = (const float*)d_in[5];
    const float* fc_c_b   = (const float*)d_in[6];
    const float* blk0_W   = (const float*)d_in[7];
    const float* blk0_b   = (const float*)d_in[8];
    const float* blk1_W   = (const float*)d_in[9];
    const float* blk1_b   = (const float*)d_in[10];
    const float* fc_out_W = (const float*)d_in[11];
    const float* fc_out_b = (const float*)d_in[12];
    float* out = (float*)d_out;

    // pick replica count that fits ws: R*(61440+4096)*2B + partials 81920B + tp 10240B
    int R = 8;
    while (R > 1 && ((size_t)R * (61440 + 4096) * 2 + 81920 + 10240) > ws_size) R >>= 1;

    _Float16* ws_w   = (_Float16*)d_ws;
    _Float16* ws_fco = ws_w + (size_t)R * 61440;
    float* partials  = (float*)(ws_fco + (size_t)R * 4096);
    float* tp        = partials + 20480;

    prep_kernel<<<112, 256, 0, stream>>>(fc_c_W, blk0_W, blk1_W, fc_out_W, tf,
                                         ws_w, ws_fco, partials, R);
    finalize_tp<<<10, 256, 0, stream>>>(partials, fc_c_b, fc_p_b, tp);
    decoder_kernel<<<GRID_, 512, 0, stream>>>(
        p, c, blk0_b, blk1_b, fc_p_W, fc_out_b, ws_w, ws_fco, tp, out, R - 1);
}

// Round 2
// 541.230 us; speedup vs baseline: 1.3684x; 1.3684x over previous
//
#include <hip/hip_runtime.h>

// AblationDecoder: B=8, N=50000, DIM=3, C_DIM=64, TASK_DIM=512, H=64, NB=5, OUT=12
// R6: R5 (weights in LDS, 256 persistent blocks x 8 waves) minus the spills.
// R5 post-mortem: FETCH 880MB / WRITE 400MB (ideal ~131MB total) at 2:1 ratio =
// scratch spill thrash; VGPR_Count=128 means the compiler split the unified
// gfx950 file 128 arch / 128 acc and the task loop + tc-dependent `break`s in
// "unrolled" loops pushed runtime-indexed arrays (net4[t], cB[t]) to scratch.
// R6 makes every loop trip count compile-time (tail task clamps reads, stores
// predicated), narrows transient live ranges (tpv for cond only, bb0/bb1 for
// the fused phase only). Arch demand ~100 <= 128; net4+X/Y (128) fit the acc
// half; MFMA reads A from AGPRs directly, so zero scratch expected.
#define B_    8
#define N_    50000
#define NB_   5
#define OUT_  12
#define TILES_ 4
#define TILES_PER_BATCH 3125              // 50000/16
#define BLOCKS_PER_BATCH 782              // ceil(3125/4)
#define NTASKS (B_ * BLOCKS_PER_BATCH)    // 6256
#define GRID_  256
#define NWAVES_TOTAL (GRID_ * 8)          // 2048

typedef _Float16 half8 __attribute__((ext_vector_type(8)));
typedef float   floatx4 __attribute__((ext_vector_type(4)));

// async 16B global->LDS (dest = wave-uniform base + lane*16)
__device__ __forceinline__ void cp16_async(const void* g, void* l) {
    __builtin_amdgcn_global_load_lds(
        (const __attribute__((address_space(1))) unsigned int*)g,
        (__attribute__((address_space(3))) unsigned int*)l,
        16, 0, 0);
}

// B fragment from two D-layout accumulators: f32->f16 (RTN), then packed relu
// (relu-after-cvt == cvt-after-relu: cvt monotone, cvt(0)=0 -> v_pk_max_f16 x4).
__device__ __forceinline__ half8 packB(floatx4 a, floatx4 b) {
    half8 r;
    r[0] = (_Float16)a[0]; r[1] = (_Float16)a[1];
    r[2] = (_Float16)a[2]; r[3] = (_Float16)a[3];
    r[4] = (_Float16)b[0]; r[5] = (_Float16)b[1];
    r[6] = (_Float16)b[2]; r[7] = (_Float16)b[3];
    half8 z = {(_Float16)0, (_Float16)0, (_Float16)0, (_Float16)0,
               (_Float16)0, (_Float16)0, (_Float16)0, (_Float16)0};
    return __builtin_elementwise_max(r, z);
}

// load one stage's 8 A-fragments from LDS (frag j = A[T*2+h]) -> ds_read_b128 x8
__device__ __forceinline__ void lds8(half8 (&A)[8], const _Float16* base, int lane) {
    #pragma unroll
    for (int T = 0; T < 4; ++T)
        #pragma unroll
        for (int h = 0; h < 2; ++h)
            A[T * 2 + h] = *(const half8*)(base + (size_t)(T * 128 + h * 64 + lane) * 8);
}

// ---------------------------------------------------------------------------
// Pre-kernel A (fused): blocks 0..31 build f16 A-fragment weights (R replicas);
// blocks 32..111 compute task-feature partial projections (8 chunks per (b,i)).
// ws_w layout per replica: chunk ((mat*5+i)*4+T)*128 + h*64 + q*16 + m15, 8 halves.
// ws_fco per replica: 512 chunks, chunks 0..127 = fc_out, rest zero. (unchanged)
// ---------------------------------------------------------------------------
__global__ void prep_kernel(const float* __restrict__ fc_c_W,
                            const float* __restrict__ blk0_W,
                            const float* __restrict__ blk1_W,
                            const float* __restrict__ fc_out_W,
                            const float* __restrict__ tf,
                            _Float16* __restrict__ ws_w,
                            _Float16* __restrict__ ws_fco,
                            float* __restrict__ partials, int R) {
    int bid = blockIdx.x, tid = threadIdx.x;
    if (bid < 32) {
        int u = bid * 256 + tid;          // 0..8191
        if (u < 7680) {
            int m15 = u & 15, q = (u >> 4) & 3, h = (u >> 6) & 1, T = (u >> 7) & 3;
            int mi = u >> 9;              // 0..14
            int mat = mi / 5, i = mi % 5;
            int n = T * 16 + m15;
            _Float16 out[8];
            #pragma unroll
            for (int j = 0; j < 8; ++j) {
                float v;
                if (mat == 0) {
                    int k = 32 * h + 8 * q + j;
                    v = fc_c_W[((size_t)i * 576 + k) * 64 + n];
                } else {
                    int f = 32 * h + 16 * (j >> 2) + 4 * q + (j & 3);
                    const float* W = (mat == 1) ? blk0_W : blk1_W;
                    v = W[((size_t)i * 64 + f) * 64 + n];
                }
                out[j] = (_Float16)v;
            }
            uint4 val = *(uint4*)out;
            for (int r = 0; r < R; ++r)
                *(uint4*)(ws_w + (size_t)r * 61440 + (size_t)u * 8) = val;
        } else {
            int e = u - 7680;             // 0..511
            _Float16 out[8] = {};
            if (e < 128) {
                int m15 = e & 15, q = (e >> 4) & 3, h = (e >> 6) & 1;
                #pragma unroll
                for (int j = 0; j < 8; ++j) {
                    int f = 32 * h + 16 * (j >> 2) + 4 * q + (j & 3);
                    out[j] = (m15 < OUT_) ? (_Float16)fc_out_W[f * OUT_ + m15] : (_Float16)0.f;
                }
            }
            uint4 val = *(uint4*)out;
            for (int r = 0; r < R; ++r)
                *(uint4*)(ws_fco + (size_t)r * 4096 + (size_t)e * 8) = val;
        }
    } else {
        // task partials: idx2 -> (b, i, half); 4 groups of 64 t's each
        int idx2 = bid - 32;              // 0..79
        int b = idx2 / 10, rem = idx2 % 10, i = rem >> 1, hf = rem & 1;
        int g = tid >> 6, j = tid & 63;
        const float* W  = fc_c_W + ((size_t)i * 576 + 64) * 64;
        const float* tb = tf + b * 512;
        int t0 = hf * 256 + g * 64;
        float acc = 0.f;
        #pragma unroll 8
        for (int t = 0; t < 64; ++t)
            acc += tb[t0 + t] * W[(size_t)(t0 + t) * 64 + j];
        partials[(((b * 5 + i) << 3) + (hf * 4 + g)) * 64 + j] = acc;
    }
}

// Pre-kernel B: tp[b][i][j] = sum_8 partials + fc_c_b + (i==0 ? fc_p_b : 0)
__global__ void finalize_tp(const float* __restrict__ partials,
                            const float* __restrict__ fc_c_b,
                            const float* __restrict__ fc_p_b,
                            float* __restrict__ tp) {
    int u = blockIdx.x * 256 + threadIdx.x;
    if (u >= 2560) return;
    int b = u / 320, rem = u % 320, i = rem >> 6, j = rem & 63;
    float s = fc_c_b[i * 64 + j] + ((i == 0) ? fc_p_b[j] : 0.f);
    #pragma unroll
    for (int k = 0; k < 8; ++k)
        s += partials[(((b * 5 + i) << 3) + k) * 64 + j];
    tp[u] = s;
}

// ---------------------------------------------------------------------------
// One resblock: cond (Ac) -> [prefetch blk1 into Ac from LDS] -> blk0 (Ab) +
// blk1 (Ac) fused per tile -> [prefetch next cond into Ab] -> [prefetch next
// blk0 into Ac]. Caller alternates (X,Y)/(Y,X). Fixed 4-tile trip counts;
// only static indexing (spill discipline).
// ---------------------------------------------------------------------------
__device__ __forceinline__ void resblock(
    half8 (&Ac)[8], half8 (&Ab)[8],
    floatx4 (&net4)[TILES_][4], const half8 (&cB)[TILES_][2],
    int i, int q, int lane,
    const float* __restrict__ tp_b, const float* __restrict__ b0g,
    const float* __restrict__ b1g, const _Float16* wlds,
    const _Float16* next_base, bool last)
{
    // ---- conditioning: net += c @ Wc + tp ----
    {
        floatx4 tpv[4];
        #pragma unroll
        for (int T = 0; T < 4; ++T)
            tpv[T] = *(const floatx4*)(tp_b + i * 64 + 16 * T + 4 * q);
        #pragma unroll
        for (int t = 0; t < TILES_; ++t) {
            #pragma unroll
            for (int T = 0; T < 4; ++T) {
                floatx4 a = net4[t][T];
                a = __builtin_amdgcn_mfma_f32_16x16x32_f16(Ac[2 * T], cB[t][0], a, 0, 0, 0);
                a = __builtin_amdgcn_mfma_f32_16x16x32_f16(Ac[2 * T + 1], cB[t][1], a, 0, 0, 0);
                net4[t][T] = a + tpv[T];
            }
        }
    }
    lds8(Ac, wlds + (size_t)(10 + i) * 4096, lane);      // prefetch blk1_i
    // ---- blk0+blk1 fused per tile ----
    {
        floatx4 bb0[4], bb1[4];
        #pragma unroll
        for (int T = 0; T < 4; ++T) {
            bb0[T] = *(const floatx4*)(b0g + i * 64 + 16 * T + 4 * q);
            bb1[T] = *(const floatx4*)(b1g + i * 64 + 16 * T + 4 * q);
        }
        #pragma unroll
        for (int t = 0; t < TILES_; ++t) {
            half8 Bn0 = packB(net4[t][0], net4[t][1]);
            half8 Bn1 = packB(net4[t][2], net4[t][3]);
            floatx4 hh[4];
            #pragma unroll
            for (int T = 0; T < 4; ++T) {
                floatx4 a = bb0[T];
                a = __builtin_amdgcn_mfma_f32_16x16x32_f16(Ab[2 * T], Bn0, a, 0, 0, 0);
                a = __builtin_amdgcn_mfma_f32_16x16x32_f16(Ab[2 * T + 1], Bn1, a, 0, 0, 0);
                hh[T] = a;
            }
            half8 Bh0 = packB(hh[0], hh[1]);
            half8 Bh1 = packB(hh[2], hh[3]);
            #pragma unroll
            for (int T = 0; T < 4; ++T) {
                floatx4 a = bb1[T];
                a = __builtin_amdgcn_mfma_f32_16x16x32_f16(Ac[2 * T], Bh0, a, 0, 0, 0);
                a = __builtin_amdgcn_mfma_f32_16x16x32_f16(Ac[2 * T + 1], Bh1, a, 0, 0, 0);
                net4[t][T] += a;
            }
        }
    }
    if (!last) {
        lds8(Ab, next_base, lane);                           // prefetch cond_{i+1}
        lds8(Ac, wlds + (size_t)(5 + i + 1) * 4096, lane);   // prefetch blk0_{i+1}
    } else {
        // fc_out: only frags 0,1 are ever used
        Ab[0] = *(const half8*)(next_base + (size_t)lane * 8);
        Ab[1] = *(const half8*)(next_base + (size_t)(64 + lane) * 8);
    }
}

// ---------------------------------------------------------------------------
// Main decoder: 256 persistent blocks x 512 threads (8 waves, 1 block/CU via
// 124,928B LDS). Weights staged to LDS once; each wave loops over 4-tile tasks.
// Replica = blockIdx & rmask aligns with default XCD round-robin dispatch.
// ---------------------------------------------------------------------------
__global__ __launch_bounds__(512, 2) void decoder_kernel(
    const float* __restrict__ p_g, const float* __restrict__ c_g,
    const float* __restrict__ blk0_b, const float* __restrict__ blk1_b,
    const float* __restrict__ fc_p_W, const float* __restrict__ fc_out_b,
    const _Float16* __restrict__ ws_w, const _Float16* __restrict__ ws_fco,
    const float* __restrict__ tp_g, float* __restrict__ out_g, int rmask)
{
    // 15 stages * 4096 halves + 1024 halves fc_out = 62464 halves = 124,928 B
    __shared__ __align__(16) _Float16 wlds[62464];

    const int tid  = threadIdx.x;
    const int wave = tid >> 6;
    const int lane = tid & 63;
    const int q = lane >> 4, m15 = lane & 15;
    const _Float16* wsr = ws_w  + (size_t)(blockIdx.x & rmask) * 61440;
    const _Float16* fcr = ws_fco + (size_t)(blockIdx.x & rmask) * 4096;

    // ---- stage all weights into LDS: 7680 weight chunks + 128 fc_out chunks ----
    #pragma unroll
    for (int k = 0; k < 16; ++k) {
        int cb = k * 512 + wave * 64;               // wave-uniform chunk base
        if (cb < 7808) {
            const _Float16* src = (cb < 7680) ? (wsr + (size_t)cb * 8)
                                              : (fcr + (size_t)(cb - 7680) * 8);
            cp16_async(src + (size_t)lane * 8, (char*)&wlds[0] + (size_t)cb * 16);
        }
    }
    __syncthreads();   // drains vmcnt(0): staging complete; LDS read-only after

    // ---- per-wave task loop ----
    for (int task = blockIdx.x * 8 + wave; task < NTASKS; task += NWAVES_TOTAL) {
        const int batch = task / BLOCKS_PER_BATCH;
        const int blk   = task - batch * BLOCKS_PER_BATCH;
        const int tile0 = blk * TILES_;
        const long gbase = (long)batch * N_ + (long)tile0 * 16;
        const float* tp_b = tp_g + batch * (NB_ * 64);

        // tail task (1 per batch, tile0=3124): clamp reads to tile 0, mask stores.
        int roff[TILES_];
        #pragma unroll
        for (int t = 0; t < TILES_; ++t)
            roff[t] = (tile0 + t < TILES_PER_BATCH) ? t * 16 : 0;

        // ---- c -> B-operand registers (global; issue first, longest latency) ----
        half8 cB[TILES_][2];
        #pragma unroll
        for (int t = 0; t < TILES_; ++t) {
            const float* cr = c_g + (size_t)(gbase + roff[t] + m15) * 64;
            #pragma unroll
            for (int h = 0; h < 2; ++h) {
                float4 v0 = *(const float4*)(cr + 32 * h + 8 * q);
                float4 v1 = *(const float4*)(cr + 32 * h + 8 * q + 4);
                half8 r;
                r[0] = (_Float16)v0.x; r[1] = (_Float16)v0.y;
                r[2] = (_Float16)v0.z; r[3] = (_Float16)v0.w;
                r[4] = (_Float16)v1.x; r[5] = (_Float16)v1.y;
                r[6] = (_Float16)v1.z; r[7] = (_Float16)v1.w;
                cB[t][h] = r;
            }
        }

        // ---- initial fragment prefetch from LDS ----
        half8 X[8], Y[8];
        lds8(X, &wlds[0], lane);                          // cond_0
        lds8(Y, &wlds[0] + (size_t)5 * 4096, lane);       // blk0_0

        // ---- net init: p @ fc_p_W (biases folded into tp[0]) ----
        floatx4 net4[TILES_][4];
        {
            floatx4 fw[3][4];
            #pragma unroll
            for (int d = 0; d < 3; ++d)
                #pragma unroll
                for (int T = 0; T < 4; ++T)
                    fw[d][T] = *(const floatx4*)(fc_p_W + d * 64 + 16 * T + 4 * q);
            #pragma unroll
            for (int t = 0; t < TILES_; ++t) {
                long g = gbase + roff[t] + m15;
                float pp0 = p_g[g * 3 + 0], pp1 = p_g[g * 3 + 1], pp2 = p_g[g * 3 + 2];
                #pragma unroll
                for (int T = 0; T < 4; ++T)
                    net4[t][T] = fw[0][T] * pp0 + fw[1][T] * pp1 + fw[2][T] * pp2;
            }
        }

        // ---- 5 resblocks, alternating prefetch buffers (all weights from LDS) ----
        resblock(X, Y, net4, cB, 0, q, lane, tp_b, blk0_b, blk1_b, &wlds[0], &wlds[0] + (size_t)1 * 4096, false);
        resblock(Y, X, net4, cB, 1, q, lane, tp_b, blk0_b, blk1_b, &wlds[0], &wlds[0] + (size_t)2 * 4096, false);
        resblock(X, Y, net4, cB, 2, q, lane, tp_b, blk0_b, blk1_b, &wlds[0], &wlds[0] + (size_t)3 * 4096, false);
        resblock(Y, X, net4, cB, 3, q, lane, tp_b, blk0_b, blk1_b, &wlds[0], &wlds[0] + (size_t)4 * 4096, false);
        resblock(X, Y, net4, cB, 4, q, lane, tp_b, blk0_b, blk1_b, &wlds[0], &wlds[0] + (size_t)61440, true);

        // ---- output: out = relu(net) @ fc_out + b  (fco frags in Y[0],Y[1]) ----
        floatx4 ob = {0.f, 0.f, 0.f, 0.f};
        if (q < 3) ob = *(const floatx4*)(fc_out_b + 4 * q);
        #pragma unroll
        for (int t = 0; t < TILES_; ++t) {
            half8 Bn0 = packB(net4[t][0], net4[t][1]);
            half8 Bn1 = packB(net4[t][2], net4[t][3]);
            floatx4 a = ob;
            a = __builtin_amdgcn_mfma_f32_16x16x32_f16(Y[0], Bn0, a, 0, 0, 0);
            a = __builtin_amdgcn_mfma_f32_16x16x32_f16(Y[1], Bn1, a, 0, 0, 0);
            if (q < 3 && tile0 + t < TILES_PER_BATCH) {
                long g = gbase + t * 16 + m15;
                *(float4*)(out_g + g * OUT_ + 4 * q) = make_float4(a[0], a[1], a[2], a[3]);
            }
        }
    }
}

// ---------------------------------------------------------------------------
extern "C" void kernel_launch(void* const* d_in, const int* in_sizes, int n_in,
                              void* d_out, int out_size, void* d_ws, size_t ws_size,
                              hipStream_t stream) {
    const float* p        = (const float*)d_in[0];
    const float* c        = (const float*)d_in[1];
    const float* tf       = (const float*)d_in[2];
    const float* fc_p_W   = (const float*)d_in[3];
    const float* fc_p_b   = (const float*)d_in[4];
    const float* fc_c_W   = (const float*)d_in[5];
    const float* fc_c_b   = (const float*)d_in[6];
    const float* blk0_W   = (const float*)d_in[7];
    const float* blk0_b   = (const float*)d_in[8];
    const float* blk1_W   = (const float*)d_in[9];
    const float* blk1_b   = (const float*)d_in[10];
    const float* fc_out_W = (const float*)d_in[11];
    const float* fc_out_b = (const float*)d_in[12];
    float* out = (float*)d_out;

    // pick replica count that fits ws: R*(61440+4096)*2B + partials 81920B + tp 10240B
    int R = 8;
    while (R > 1 && ((size_t)R * (61440 + 4096) * 2 + 81920 + 10240) > ws_size) R >>= 1;

    _Float16* ws_w   = (_Float16*)d_ws;
    _Float16* ws_fco = ws_w + (size_t)R * 61440;
    float* partials  = (float*)(ws_fco + (size_t)R * 4096);
    float* tp        = partials + 20480;

    prep_kernel<<<112, 256, 0, stream>>>(fc_c_W, blk0_W, blk1_W, fc_out_W, tf,
                                         ws_w, ws_fco, partials, R);
    finalize_tp<<<10, 256, 0, stream>>>(partials, fc_c_b, fc_p_b, tp);
    decoder_kernel<<<GRID_, 512, 0, stream>>>(
        p, c, blk0_b, blk1_b, fc_p_W, fc_out_b, ws_w, ws_fco, tp, out, R - 1);
}

// Round 3
// 236.151 us; speedup vs baseline: 3.1363x; 2.2919x over previous
//
#include <hip/hip_runtime.h>

// AblationDecoder: B=8, N=50000, DIM=3, C_DIM=64, TASK_DIM=512, H=64, NB=5, OUT=12
// R7: R6 minus the LICM-induced spills.
// R6 post-mortem: still ~347MB scratch writes / ~470MB reloads with VGPR=128.
// Cause: inside the persistent task loop the bias/weight loads (blk0_b/blk1_b
// = 160 values across 5 resblocks, fw = 48, ob = 4) are loop-invariant; LICM
// hoists them, regalloc can't keep them live across the loop within the
// 256-reg/wave cap (512-thr block = 2 waves/SIMD), so they spill and thrash
// scratch every iteration. R4 (no loop) fit in 124 VGPRs with the same body.
// Fix: (a) launder loop-invariant pointers + a zero LDS offset through
// asm volatile inside the loop, making every such load formally loop-variant
// (unhoistable; reloads are L1/LDS-hot); (b) TILES_ 4->3 for ~40 regs slack
// (net4 48, cB 24) and a better wave tail (1.23x vs 1.31x). Steady-state
// demand ~200 < 256 -> zero scratch expected.
#define B_    8
#define N_    50000
#define NB_   5
#define OUT_  12
#define TILES_ 3
#define TILES_PER_BATCH 3125              // 50000/16
#define TASKS_PER_BATCH 1042              // ceil(3125/3)
#define NTASKS (B_ * TASKS_PER_BATCH)     // 8336
#define GRID_  256
#define NWAVES_TOTAL (GRID_ * 8)          // 2048

typedef _Float16 half8 __attribute__((ext_vector_type(8)));
typedef float   floatx4 __attribute__((ext_vector_type(4)));

// async 16B global->LDS (dest = wave-uniform base + lane*16)
__device__ __forceinline__ void cp16_async(const void* g, void* l) {
    __builtin_amdgcn_global_load_lds(
        (const __attribute__((address_space(1))) unsigned int*)g,
        (__attribute__((address_space(3))) unsigned int*)l,
        16, 0, 0);
}

// launder a pointer through an opaque asm so loads from it can't be LICM-hoisted
__device__ __forceinline__ const float* lf(const float* p) {
    unsigned long long u = (unsigned long long)p;
    asm volatile("" : "+s"(u));
    return (const float*)u;
}

// B fragment from two D-layout accumulators: f32->f16 (RTN), then packed relu
// (relu-after-cvt == cvt-after-relu: cvt monotone, cvt(0)=0 -> v_pk_max_f16 x4).
__device__ __forceinline__ half8 packB(floatx4 a, floatx4 b) {
    half8 r;
    r[0] = (_Float16)a[0]; r[1] = (_Float16)a[1];
    r[2] = (_Float16)a[2]; r[3] = (_Float16)a[3];
    r[4] = (_Float16)b[0]; r[5] = (_Float16)b[1];
    r[6] = (_Float16)b[2]; r[7] = (_Float16)b[3];
    half8 z = {(_Float16)0, (_Float16)0, (_Float16)0, (_Float16)0,
               (_Float16)0, (_Float16)0, (_Float16)0, (_Float16)0};
    return __builtin_elementwise_max(r, z);
}

// load one stage's 8 A-fragments from LDS (frag j = A[T*2+h]) -> ds_read_b128 x8
__device__ __forceinline__ void lds8(half8 (&A)[8], const _Float16* base, int lane) {
    #pragma unroll
    for (int T = 0; T < 4; ++T)
        #pragma unroll
        for (int h = 0; h < 2; ++h)
            A[T * 2 + h] = *(const half8*)(base + (size_t)(T * 128 + h * 64 + lane) * 8);
}

// ---------------------------------------------------------------------------
// Pre-kernel A (fused): blocks 0..31 build f16 A-fragment weights (R replicas);
// blocks 32..111 compute task-feature partial projections (8 chunks per (b,i)).
// ws_w layout per replica: chunk ((mat*5+i)*4+T)*128 + h*64 + q*16 + m15, 8 halves.
// ws_fco per replica: 512 chunks, chunks 0..127 = fc_out, rest zero. (unchanged)
// ---------------------------------------------------------------------------
__global__ void prep_kernel(const float* __restrict__ fc_c_W,
                            const float* __restrict__ blk0_W,
                            const float* __restrict__ blk1_W,
                            const float* __restrict__ fc_out_W,
                            const float* __restrict__ tf,
                            _Float16* __restrict__ ws_w,
                            _Float16* __restrict__ ws_fco,
                            float* __restrict__ partials, int R) {
    int bid = blockIdx.x, tid = threadIdx.x;
    if (bid < 32) {
        int u = bid * 256 + tid;          // 0..8191
        if (u < 7680) {
            int m15 = u & 15, q = (u >> 4) & 3, h = (u >> 6) & 1, T = (u >> 7) & 3;
            int mi = u >> 9;              // 0..14
            int mat = mi / 5, i = mi % 5;
            int n = T * 16 + m15;
            _Float16 out[8];
            #pragma unroll
            for (int j = 0; j < 8; ++j) {
                float v;
                if (mat == 0) {
                    int k = 32 * h + 8 * q + j;
                    v = fc_c_W[((size_t)i * 576 + k) * 64 + n];
                } else {
                    int f = 32 * h + 16 * (j >> 2) + 4 * q + (j & 3);
                    const float* W = (mat == 1) ? blk0_W : blk1_W;
                    v = W[((size_t)i * 64 + f) * 64 + n];
                }
                out[j] = (_Float16)v;
            }
            uint4 val = *(uint4*)out;
            for (int r = 0; r < R; ++r)
                *(uint4*)(ws_w + (size_t)r * 61440 + (size_t)u * 8) = val;
        } else {
            int e = u - 7680;             // 0..511
            _Float16 out[8] = {};
            if (e < 128) {
                int m15 = e & 15, q = (e >> 4) & 3, h = (e >> 6) & 1;
                #pragma unroll
                for (int j = 0; j < 8; ++j) {
                    int f = 32 * h + 16 * (j >> 2) + 4 * q + (j & 3);
                    out[j] = (m15 < OUT_) ? (_Float16)fc_out_W[f * OUT_ + m15] : (_Float16)0.f;
                }
            }
            uint4 val = *(uint4*)out;
            for (int r = 0; r < R; ++r)
                *(uint4*)(ws_fco + (size_t)r * 4096 + (size_t)e * 8) = val;
        }
    } else {
        // task partials: idx2 -> (b, i, half); 4 groups of 64 t's each
        int idx2 = bid - 32;              // 0..79
        int b = idx2 / 10, rem = idx2 % 10, i = rem >> 1, hf = rem & 1;
        int g = tid >> 6, j = tid & 63;
        const float* W  = fc_c_W + ((size_t)i * 576 + 64) * 64;
        const float* tb = tf + b * 512;
        int t0 = hf * 256 + g * 64;
        float acc = 0.f;
        #pragma unroll 8
        for (int t = 0; t < 64; ++t)
            acc += tb[t0 + t] * W[(size_t)(t0 + t) * 64 + j];
        partials[(((b * 5 + i) << 3) + (hf * 4 + g)) * 64 + j] = acc;
    }
}

// Pre-kernel B: tp[b][i][j] = sum_8 partials + fc_c_b + (i==0 ? fc_p_b : 0)
__global__ void finalize_tp(const float* __restrict__ partials,
                            const float* __restrict__ fc_c_b,
                            const float* __restrict__ fc_p_b,
                            float* __restrict__ tp) {
    int u = blockIdx.x * 256 + threadIdx.x;
    if (u >= 2560) return;
    int b = u / 320, rem = u % 320, i = rem >> 6, j = rem & 63;
    float s = fc_c_b[i * 64 + j] + ((i == 0) ? fc_p_b[j] : 0.f);
    #pragma unroll
    for (int k = 0; k < 8; ++k)
        s += partials[(((b * 5 + i) << 3) + k) * 64 + j];
    tp[u] = s;
}

// ---------------------------------------------------------------------------
// One resblock: cond (Ac) -> [prefetch blk1 into Ac from LDS] -> blk0 (Ab) +
// blk1 (Ac) fused per tile -> [prefetch next cond into Ab] -> [prefetch next
// blk0 into Ac]. Caller alternates (X,Y)/(Y,X). Fixed trip counts; static
// indexing only; all global pointers passed in are laundered per task.
// ---------------------------------------------------------------------------
__device__ __forceinline__ void resblock(
    half8 (&Ac)[8], half8 (&Ab)[8],
    floatx4 (&net4)[TILES_][4], const half8 (&cB)[TILES_][2],
    int i, int q, int lane,
    const float* __restrict__ tp_b, const float* __restrict__ b0g,
    const float* __restrict__ b1g, const _Float16* wlds,
    const _Float16* next_base, bool last)
{
    // ---- conditioning: net += c @ Wc + tp ----
    {
        floatx4 tpv[4];
        #pragma unroll
        for (int T = 0; T < 4; ++T)
            tpv[T] = *(const floatx4*)(tp_b + i * 64 + 16 * T + 4 * q);
        #pragma unroll
        for (int t = 0; t < TILES_; ++t) {
            #pragma unroll
            for (int T = 0; T < 4; ++T) {
                floatx4 a = net4[t][T];
                a = __builtin_amdgcn_mfma_f32_16x16x32_f16(Ac[2 * T], cB[t][0], a, 0, 0, 0);
                a = __builtin_amdgcn_mfma_f32_16x16x32_f16(Ac[2 * T + 1], cB[t][1], a, 0, 0, 0);
                net4[t][T] = a + tpv[T];
            }
        }
    }
    lds8(Ac, wlds + (size_t)(10 + i) * 4096, lane);      // prefetch blk1_i
    // ---- blk0+blk1 fused per tile ----
    {
        floatx4 bb0[4], bb1[4];
        #pragma unroll
        for (int T = 0; T < 4; ++T) {
            bb0[T] = *(const floatx4*)(b0g + i * 64 + 16 * T + 4 * q);
            bb1[T] = *(const floatx4*)(b1g + i * 64 + 16 * T + 4 * q);
        }
        #pragma unroll
        for (int t = 0; t < TILES_; ++t) {
            half8 Bn0 = packB(net4[t][0], net4[t][1]);
            half8 Bn1 = packB(net4[t][2], net4[t][3]);
            floatx4 hh[4];
            #pragma unroll
            for (int T = 0; T < 4; ++T) {
                floatx4 a = bb0[T];
                a = __builtin_amdgcn_mfma_f32_16x16x32_f16(Ab[2 * T], Bn0, a, 0, 0, 0);
                a = __builtin_amdgcn_mfma_f32_16x16x32_f16(Ab[2 * T + 1], Bn1, a, 0, 0, 0);
                hh[T] = a;
            }
            half8 Bh0 = packB(hh[0], hh[1]);
            half8 Bh1 = packB(hh[2], hh[3]);
            #pragma unroll
            for (int T = 0; T < 4; ++T) {
                floatx4 a = bb1[T];
                a = __builtin_amdgcn_mfma_f32_16x16x32_f16(Ac[2 * T], Bh0, a, 0, 0, 0);
                a = __builtin_amdgcn_mfma_f32_16x16x32_f16(Ac[2 * T + 1], Bh1, a, 0, 0, 0);
                net4[t][T] += a;
            }
        }
    }
    if (!last) {
        lds8(Ab, next_base, lane);                           // prefetch cond_{i+1}
        lds8(Ac, wlds + (size_t)(5 + i + 1) * 4096, lane);   // prefetch blk0_{i+1}
    } else {
        // fc_out: only frags 0,1 are ever used
        Ab[0] = *(const half8*)(next_base + (size_t)lane * 8);
        Ab[1] = *(const half8*)(next_base + (size_t)(64 + lane) * 8);
    }
}

// ---------------------------------------------------------------------------
// Main decoder: 256 persistent blocks x 512 threads (8 waves, 1 block/CU via
// 124,928B LDS). Weights staged to LDS once; each wave loops over 3-tile tasks.
// ---------------------------------------------------------------------------
__global__ __launch_bounds__(512, 2) void decoder_kernel(
    const float* __restrict__ p_g, const float* __restrict__ c_g,
    const float* __restrict__ blk0_b, const float* __restrict__ blk1_b,
    const float* __restrict__ fc_p_W, const float* __restrict__ fc_out_b,
    const _Float16* __restrict__ ws_w, const _Float16* __restrict__ ws_fco,
    const float* __restrict__ tp_g, float* __restrict__ out_g, int rmask)
{
    // 15 stages * 4096 halves + 1024 halves fc_out = 62464 halves = 124,928 B
    __shared__ __align__(16) _Float16 wlds[62464];

    const int tid  = threadIdx.x;
    const int wave = tid >> 6;
    const int lane = tid & 63;
    const int q = lane >> 4, m15 = lane & 15;
    const _Float16* wsr = ws_w  + (size_t)(blockIdx.x & rmask) * 61440;
    const _Float16* fcr = ws_fco + (size_t)(blockIdx.x & rmask) * 4096;

    // ---- stage all weights into LDS: 7680 weight chunks + 128 fc_out chunks ----
    #pragma unroll
    for (int k = 0; k < 16; ++k) {
        int cb = k * 512 + wave * 64;               // wave-uniform chunk base
        if (cb < 7808) {
            const _Float16* src = (cb < 7680) ? (wsr + (size_t)cb * 8)
                                              : (fcr + (size_t)(cb - 7680) * 8);
            cp16_async(src + (size_t)lane * 8, (char*)&wlds[0] + (size_t)cb * 16);
        }
    }
    __syncthreads();   // drains vmcnt(0): staging complete; LDS read-only after

    // ---- per-wave task loop ----
    for (int task = blockIdx.x * 8 + wave; task < NTASKS; task += NWAVES_TOTAL) {
        // launder loop-invariant bases: loads below become formally loop-variant
        // so LICM cannot hoist them into loop-carried (spilled) registers.
        const float* b0g = lf(blk0_b);
        const float* b1g = lf(blk1_b);
        const float* fpw = lf(fc_p_W);
        const float* fob = lf(fc_out_b);
        int zofs = 0;
        asm volatile("" : "+v"(zofs));
        const _Float16* wl = &wlds[0] + zofs;

        const int batch = task / TASKS_PER_BATCH;
        const int blk   = task - batch * TASKS_PER_BATCH;
        const int tile0 = blk * TILES_;
        const long gbase = (long)batch * N_ + (long)tile0 * 16;
        const float* tp_b = tp_g + batch * (NB_ * 64);

        // tail task (1 per batch): clamp reads to tile 0, mask stores.
        int roff[TILES_];
        #pragma unroll
        for (int t = 0; t < TILES_; ++t)
            roff[t] = (tile0 + t < TILES_PER_BATCH) ? t * 16 : 0;

        // ---- c -> B-operand registers (global; issue first, longest latency) ----
        half8 cB[TILES_][2];
        #pragma unroll
        for (int t = 0; t < TILES_; ++t) {
            const float* cr = c_g + (size_t)(gbase + roff[t] + m15) * 64;
            #pragma unroll
            for (int h = 0; h < 2; ++h) {
                float4 v0 = *(const float4*)(cr + 32 * h + 8 * q);
                float4 v1 = *(const float4*)(cr + 32 * h + 8 * q + 4);
                half8 r;
                r[0] = (_Float16)v0.x; r[1] = (_Float16)v0.y;
                r[2] = (_Float16)v0.z; r[3] = (_Float16)v0.w;
                r[4] = (_Float16)v1.x; r[5] = (_Float16)v1.y;
                r[6] = (_Float16)v1.z; r[7] = (_Float16)v1.w;
                cB[t][h] = r;
            }
        }

        // ---- initial fragment prefetch from LDS ----
        half8 X[8], Y[8];
        lds8(X, wl, lane);                          // cond_0
        lds8(Y, wl + (size_t)5 * 4096, lane);       // blk0_0

        // ---- net init: p @ fc_p_W (biases folded into tp[0]) ----
        floatx4 net4[TILES_][4];
        {
            floatx4 fw[3][4];
            #pragma unroll
            for (int d = 0; d < 3; ++d)
                #pragma unroll
                for (int T = 0; T < 4; ++T)
                    fw[d][T] = *(const floatx4*)(fpw + d * 64 + 16 * T + 4 * q);
            #pragma unroll
            for (int t = 0; t < TILES_; ++t) {
                long g = gbase + roff[t] + m15;
                float pp0 = p_g[g * 3 + 0], pp1 = p_g[g * 3 + 1], pp2 = p_g[g * 3 + 2];
                #pragma unroll
                for (int T = 0; T < 4; ++T)
                    net4[t][T] = fw[0][T] * pp0 + fw[1][T] * pp1 + fw[2][T] * pp2;
            }
        }

        // ---- 5 resblocks, alternating prefetch buffers (all weights from LDS) ----
        resblock(X, Y, net4, cB, 0, q, lane, tp_b, b0g, b1g, wl, wl + (size_t)1 * 4096, false);
        resblock(Y, X, net4, cB, 1, q, lane, tp_b, b0g, b1g, wl, wl + (size_t)2 * 4096, false);
        resblock(X, Y, net4, cB, 2, q, lane, tp_b, b0g, b1g, wl, wl + (size_t)3 * 4096, false);
        resblock(Y, X, net4, cB, 3, q, lane, tp_b, b0g, b1g, wl, wl + (size_t)4 * 4096, false);
        resblock(X, Y, net4, cB, 4, q, lane, tp_b, b0g, b1g, wl, wl + (size_t)61440, true);

        // ---- output: out = relu(net) @ fc_out + b  (fco frags in Y[0],Y[1]) ----
        floatx4 ob = {0.f, 0.f, 0.f, 0.f};
        if (q < 3) ob = *(const floatx4*)(fob + 4 * q);
        #pragma unroll
        for (int t = 0; t < TILES_; ++t) {
            half8 Bn0 = packB(net4[t][0], net4[t][1]);
            half8 Bn1 = packB(net4[t][2], net4[t][3]);
            floatx4 a = ob;
            a = __builtin_amdgcn_mfma_f32_16x16x32_f16(Y[0], Bn0, a, 0, 0, 0);
            a = __builtin_amdgcn_mfma_f32_16x16x32_f16(Y[1], Bn1, a, 0, 0, 0);
            if (q < 3 && tile0 + t < TILES_PER_BATCH) {
                long g = gbase + t * 16 + m15;
                *(float4*)(out_g + g * OUT_ + 4 * q) = make_float4(a[0], a[1], a[2], a[3]);
            }
        }
    }
}

// ---------------------------------------------------------------------------
extern "C" void kernel_launch(void* const* d_in, const int* in_sizes, int n_in,
                              void* d_out, int out_size, void* d_ws, size_t ws_size,
                              hipStream_t stream) {
    const float* p        = (const float*)d_in[0];
    const float* c        = (const float*)d_in[1];
    const float* tf       = (const float*)d_in[2];
    const float* fc_p_W   = (const float*)d_in[3];
    const float* fc_p_b   = (const float*)d_in[4];
    const float* fc_c_W   = (const float*)d_in[5];
    const float* fc_c_b   = (const float*)d_in[6];
    const float* blk0_W   = (const float*)d_in[7];
    const float* blk0_b   = (const float*)d_in[8];
    const float* blk1_W   = (const float*)d_in[9];
    const float* blk1_b   = (const float*)d_in[10];
    const float* fc_out_W = (const float*)d_in[11];
    const float* fc_out_b = (const float*)d_in[12];
    float* out = (float*)d_out;

    // pick replica count that fits ws: R*(61440+4096)*2B + partials 81920B + tp 10240B
    int R = 8;
    while (R > 1 && ((size_t)R * (61440 + 4096) * 2 + 81920 + 10240) > ws_size) R >>= 1;

    _Float16* ws_w   = (_Float16*)d_ws;
    _Float16* ws_fco = ws_w + (size_t)R * 61440;
    float* partials  = (float*)(ws_fco + (size_t)R * 4096);
    float* tp        = partials + 20480;

    prep_kernel<<<112, 256, 0, stream>>>(fc_c_W, blk0_W, blk1_W, fc_out_W, tf,
                                         ws_w, ws_fco, partials, R);
    finalize_tp<<<10, 256, 0, stream>>>(partials, fc_c_b, fc_p_b, tp);
    decoder_kernel<<<GRID_, 512, 0, stream>>>(
        p, c, blk0_b, blk1_b, fc_p_W, fc_out_b, ws_w, ws_fco, tp, out, R - 1);
}